// Round 4
// baseline (150.687 us; speedup 1.0000x reference)
//
#include <hip/hip_runtime.h>

typedef __attribute__((ext_vector_type(8))) short short8;
typedef __attribute__((ext_vector_type(4))) float f32x4;

#define NEG_SLOPE 0.02f

static __device__ __forceinline__ unsigned short f2bf(float f) {
    unsigned int u = __float_as_uint(f);
    u += 0x7fffu + ((u >> 16) & 1u);
    return (unsigned short)(u >> 16);
}

// ---------------- prep: weight transforms ----------------
// wb[co][tap][ci]  bf16  (64*9*64)   from conv_w[co][ci][dy][dx]
// pwb[o][k] = bf16(pred_w[o][k]) for o<24, 0 pad to 32 rows  (32*768 bf16)
__global__ __launch_bounds__(256) void prep_kernel(const float* __restrict__ conv_w,
                                                   const float* __restrict__ pred_w,
                                                   unsigned short* __restrict__ wb,
                                                   unsigned short* __restrict__ pwb) {
    int i = blockIdx.x * 256 + threadIdx.x;
    if (i < 36864) {
        int ci = i & 63, tap = (i >> 6) % 9, co = i / 576;
        wb[i] = f2bf(conv_w[(co * 64 + ci) * 9 + tap]);
    }
    if (i < 24576) {
        int o = i / 768, k = i - o * 768;
        pwb[i] = f2bf(o < 24 ? pred_w[o * 768 + k] : 0.0f);
    }
}

// ---------------- NCHW f32 -> NHWC bf16 transpose ----------------
// block: one b x 128-px tile. LDS bounce [64 ci][132 px] f32 (pad 132: 16B-aligned
// float4 rows, write 8/bank uniform, read 2-way). Readout: thread = (px, ci-half),
// packs 32 ci -> 4 uint4, 64B/thread contiguous NHWC store.
__global__ __launch_bounds__(256) void nchw2nhwc(const float* __restrict__ x,
                                                 unsigned short* __restrict__ xh) {
    __shared__ float t[64 * 132];
    const int bid = blockIdx.x;              // 32 b * 128 tiles
    const int b = bid >> 7, tile = bid & 127;
    const float* xb = x + ((size_t)b << 20) + tile * 128;
    const int tid = threadIdx.x;

    for (int j = tid; j < 2048; j += 256) {
        int ci = j >> 5, f4 = j & 31;
        float4 v = *(const float4*)(xb + (size_t)ci * 16384 + f4 * 4);
        *(float4*)&t[ci * 132 + f4 * 4] = v;
    }
    __syncthreads();

    const int px = tid >> 1, half = tid & 1;
    const float* col = t + (half * 32) * 132 + px;
    unsigned int o[16];
#pragma unroll
    for (int d = 0; d < 16; ++d) {
        float f0 = col[(2 * d) * 132];
        float f1 = col[(2 * d + 1) * 132];
        o[d] = (unsigned int)f2bf(f0) | ((unsigned int)f2bf(f1) << 16);
    }
    unsigned short* dst = xh + ((size_t)(b * 16384 + tile * 128 + px)) * 64 + half * 32;
#pragma unroll
    for (int d = 0; d < 4; ++d)
        *(uint4*)(dst + d * 8) = *(uint4*)&o[d * 4];
}

// ---------------- conv 3x3 + bias + leaky relu via MFMA implicit GEMM ----------------
// block: one (b, y) output row: 128 px x 64 co. 256 thr = 4 waves, wave = 32 px x 64 co.
// 9 taps x 2 ci-chunks of 32; each (tap, chunk) is one 16x16x32 MFMA K-step.
// in_sm: pixel pair stride 128 B; 8 slots of 16 B; slot = ((px&1)<<2 | q) ^ ((px>>1)&7).
// Staging from NHWC bf16: one uint4 load (8 ci of one px) -> one ds_write_b128; wave
// covers 1024 contiguous LDS bytes -> uniform 8 dw/bank (b128 floor). OOB -> zero vec.
#define ROW_BYTES (65 * 128) // 8320
__global__ __launch_bounds__(256) void conv_mfma(const unsigned short* __restrict__ xh,
                                                 const unsigned short* __restrict__ wb,
                                                 const float* __restrict__ cb,
                                                 unsigned short* __restrict__ h) {
    __shared__ unsigned short w_sm[64 * 296];            // [co][288 + 8 pad]  37,888 B
    __shared__ unsigned char in_sm[3 * ROW_BYTES];       // 24,960 B

    // XCD-chunked swizzle: each XCD gets 16 contiguous y rows x all b
    const int id = blockIdx.x;
    const int xcd = id & 7, local = id >> 3;
    const int b = local & 31;
    const int y = (xcd << 4) + (local >> 5);

    const int tid = threadIdx.x;
    const int wave = tid >> 6, lane = tid & 63;
    const int lr = lane & 15, kg = lane >> 4;
    const int x0w = wave * 32;

    f32x4 acc[2][4];
#pragma unroll
    for (int m = 0; m < 2; ++m)
#pragma unroll
        for (int n = 0; n < 4; ++n) acc[m][n] = (f32x4){0.f, 0.f, 0.f, 0.f};

    // A-frag base pointers: 2 m-tiles x 3 dx (dy adds r*ROW_BYTES at use)
    const unsigned char* ab[2][3];
#pragma unroll
    for (int m = 0; m < 2; ++m)
#pragma unroll
        for (int dx = 0; dx < 3; ++dx) {
            int pix = x0w + m * 16 + lr + dx;
            int pair = pix >> 1, odd = pix & 1;
            int slot = ((odd << 2) | kg) ^ (pair & 7);
            ab[m][dx] = in_sm + pair * 128 + slot * 16;
        }
    const unsigned short* bb[4];
#pragma unroll
    for (int n = 0; n < 4; ++n) bb[n] = w_sm + (n * 16 + lr) * 296 + kg * 8;

    for (int cc = 0; cc < 2; ++cc) {
        __syncthreads();
        // ---- stage weights: [co][tap*32 + ci'] (+8 pad), 2304 x 16B ----
        for (int j = tid; j < 2304; j += 256) {
            int q = j & 3, tap = (j >> 2) % 9, co = j / 36;
            uint4 v = *(const uint4*)(wb + (co * 9 + tap) * 64 + cc * 32 + q * 8);
            *(uint4*)(w_sm + co * 296 + tap * 32 + q * 8) = v;
        }
        // ---- stage input: NHWC bf16, 16B per thread-iter, zero on OOB ----
        for (int s = tid; s < 1560; s += 256) {            // 3 rows * 130 px * 4 chunks
            int r = s / 520, rem = s - r * 520;
            int px = rem >> 2, q = rem & 3;
            int gy = y + r - 1, gx = px - 1;
            uint4 v = {0u, 0u, 0u, 0u};
            if (gy >= 0 && gy < 128 && gx >= 0 && gx < 128)
                v = *(const uint4*)(xh + ((((size_t)b * 128 + gy) * 128 + gx) * 64 + cc * 32 + q * 8));
            int pair = px >> 1, odd = px & 1;
            int slot = ((odd << 2) | q) ^ (pair & 7);
            *(uint4*)(in_sm + r * ROW_BYTES + pair * 128 + slot * 16) = v;
        }
        __syncthreads();

        // ---- compute: 9 taps, each one K=32 MFMA step ----
#pragma unroll
        for (int t = 0; t < 9; ++t) {
            const int dy = t / 3, dx = t % 3;
            const int aoff = dy * ROW_BYTES;     // byte offset
            short8 a0 = *(const short8*)(ab[0][dx] + aoff);
            short8 a1 = *(const short8*)(ab[1][dx] + aoff);
#pragma unroll
            for (int n = 0; n < 4; ++n) {
                short8 bf = *(const short8*)(bb[n] + t * 32);
                acc[0][n] = __builtin_amdgcn_mfma_f32_16x16x32_bf16(a0, bf, acc[0][n], 0, 0, 0);
                acc[1][n] = __builtin_amdgcn_mfma_f32_16x16x32_bf16(a1, bf, acc[1][n], 0, 0, 0);
            }
        }
    }

    // ---- epilogue: bias + leaky relu, bf16 NHWC store ----
    float bias[4];
#pragma unroll
    for (int n = 0; n < 4; ++n) bias[n] = cb[n * 16 + lr];
    const size_t hrow = (size_t)(b * 128 + y) * 128;
#pragma unroll
    for (int m = 0; m < 2; ++m)
#pragma unroll
        for (int r = 0; r < 4; ++r) {
            const int p = x0w + m * 16 + kg * 4 + r;
            unsigned short* hp = h + (hrow + p) * 64 + lr;
#pragma unroll
            for (int n = 0; n < 4; ++n) {
                float v = acc[m][n][r] + bias[n];
                v = v > 0.0f ? v : NEG_SLOPE * v;
                hp[n * 16] = f2bf(v);
            }
        }
}

// ---------------- gather + (pairs x 768)·(768 x 24) GEMM via MFMA ----------------
__global__ __launch_bounds__(256) void gather_gemm(const unsigned short* __restrict__ h,
                                                   const int* __restrict__ pos,
                                                   const unsigned short* __restrict__ pw,
                                                   const float* __restrict__ pred_b,
                                                   float* __restrict__ out) {
    __shared__ unsigned char pw_lds[32 * 1536];   // 32 rows x 768 bf16, swizzled
    const int tid = threadIdx.x;

    for (int i = tid; i < 3072; i += 256) {       // 3072 chunks of 16B
        int row = i / 96, c = i - row * 96;
        int dst = row * 1536 + ((c * 16) ^ ((row & 7) << 4));
        *(uint4*)(pw_lds + dst) = ((const uint4*)pw)[i];
    }
    __syncthreads();

    const int wave = tid >> 6, lane = tid & 63;
    const int pair_base = blockIdx.x * 64 + wave * 16;
    const int prow = lane & 15;
    const int kgrp = lane >> 4;
    const int pair = pair_base + prow;
    const int b = pair & 31;
    const unsigned short* hb = h + (size_t)b * 16384 * 64;

    const int swz0 = (prow & 7) << 4;
    const unsigned char* bro0 = pw_lds + prow * 1536;
    const unsigned char* bro1 = pw_lds + (prow + 16) * 1536;

    f32x4 acc0 = {0.f, 0.f, 0.f, 0.f};
    f32x4 acc1 = {0.f, 0.f, 0.f, 0.f};

#pragma unroll
    for (int l = 0; l < 12; ++l) {
        int2 pq = ((const int2*)pos)[pair * 12 + l];
        int px = pq.x < 0 ? 0 : (pq.x > 127 ? 127 : pq.x);
        int py = pq.y < 0 ? 0 : (pq.y > 127 ? 127 : pq.y);
        const unsigned short* pix = hb + (((size_t)py << 7) + px) * 64;
#pragma unroll
        for (int half = 0; half < 2; ++half) {
            const int c0 = half * 32 + kgrp * 8;
            short8 a = *(const short8*)(pix + c0);
            const int kb = (l * 64 + half * 32 + kgrp * 8) * 2;
            short8 b0 = *(const short8*)(bro0 + (kb ^ swz0));
            short8 b1 = *(const short8*)(bro1 + (kb ^ swz0));
            acc0 = __builtin_amdgcn_mfma_f32_16x16x32_bf16(a, b0, acc0, 0, 0, 0);
            acc1 = __builtin_amdgcn_mfma_f32_16x16x32_bf16(a, b1, acc1, 0, 0, 0);
        }
    }

    const int o0 = lane & 15;
    const float bias0 = pred_b[o0];
    const float bias1 = (o0 + 16 < 24) ? pred_b[o0 + 16] : 0.0f;
#pragma unroll
    for (int r = 0; r < 4; ++r) {
        const int pout = pair_base + (lane >> 4) * 4 + r;
        out[(size_t)pout * 24 + o0] = acc0[r] + bias0;
        if (o0 + 16 < 24)
            out[(size_t)pout * 24 + o0 + 16] = acc1[r] + bias1;
    }
}

extern "C" void kernel_launch(void* const* d_in, const int* in_sizes, int n_in,
                              void* d_out, int out_size, void* d_ws, size_t ws_size,
                              hipStream_t stream) {
    const float* x      = (const float*)d_in[0];
    const int*   pos    = (const int*)d_in[1];
    const float* conv_w = (const float*)d_in[2];
    const float* conv_b = (const float*)d_in[3];
    const float* pred_w = (const float*)d_in[4];
    const float* pred_b = (const float*)d_in[5];
    float* out = (float*)d_out;

    char* ws = (char*)d_ws;
    unsigned short* xh  = (unsigned short*)ws;                         // 67,108,864 B
    unsigned short* h   = (unsigned short*)(ws + 67108864);            // 67,108,864 B
    unsigned short* wb  = (unsigned short*)(ws + 134217728);           // 73,728 B
    unsigned short* pwb = (unsigned short*)(ws + 134217728 + 73728);   // 49,152 B

    prep_kernel<<<144, 256, 0, stream>>>(conv_w, pred_w, wb, pwb);
    nchw2nhwc<<<4096, 256, 0, stream>>>(x, xh);
    conv_mfma<<<4096, 256, 0, stream>>>(xh, wb, conv_b, h);
    gather_gemm<<<500, 256, 0, stream>>>(h, pos, pwb, pred_b, out);
}

// Round 5
// 116.648 us; speedup vs baseline: 1.2918x; 1.2918x over previous
//
#include <hip/hip_runtime.h>
#include <hip/hip_bf16.h>

typedef __attribute__((ext_vector_type(8))) short short8;
typedef __attribute__((ext_vector_type(4))) float f32x4;

#define NEG_SLOPE 0.02f

static __device__ __forceinline__ unsigned short f2bf(float f) {
    unsigned int u = __float_as_uint(f);
    u += 0x7fffu + ((u >> 16) & 1u);
    return (unsigned short)(u >> 16);
}

// pack two f32 -> one dword of 2 bf16 (lo, hi) via v_cvt_pk_bf16_f32
static __device__ __forceinline__ unsigned int pk2bf(float lo, float hi) {
    __hip_bfloat162 t = __float22bfloat162_rn(float2{lo, hi});
    unsigned int u;
    __builtin_memcpy(&u, &t, 4);
    return u;
}

// ---------------- prep: weight transforms ----------------
// wb[co][tap][ci]  bf16  (64*9*64)   from conv_w[co][ci][dy][dx]
// pwb[o][k] = bf16(pred_w[o][k]) for o<24, 0 pad to 32 rows  (32*768 bf16)
__global__ __launch_bounds__(256) void prep_kernel(const float* __restrict__ conv_w,
                                                   const float* __restrict__ pred_w,
                                                   unsigned short* __restrict__ wb,
                                                   unsigned short* __restrict__ pwb) {
    int i = blockIdx.x * 256 + threadIdx.x;
    if (i < 36864) {
        int ci = i & 63, tap = (i >> 6) % 9, co = i / 576;
        wb[i] = f2bf(conv_w[(co * 64 + ci) * 9 + tap]);
    }
    if (i < 24576) {
        int o = i / 768, k = i - o * 768;
        pwb[i] = f2bf(o < 24 ? pred_w[o * 768 + k] : 0.0f);
    }
}

// ---------------- conv 3x3 + bias + leaky relu via MFMA implicit GEMM ----------------
// block: 2 output rows (y0, y0+1) x 128 px x 64 co. 4 waves; wave = one row-half:
// (ro = wave>>1, px0 = (wave&1)*64) -> 64 px x 64 co = 4 m-tiles x 4 n-tiles.
// K = 64 ci x 9 taps, split in 2 ci-chunks of 32 (one 16x16x32 MFMA K-step per tap).
//
// in_sm: 4 input rows (y0-1..y0+2); pixel pair (xx>>1) stride 128 B, 8 slots of 16 B;
// slot = ((xx&1)<<2 | q) ^ ((xx>>2)&7)   (q = ci-oct within chunk)
// Key (xx>>2)&7 is constant within a pair (closure/bijective -> correct), and at
// fixed t the 32 staging lanes (xx=4*g4+1+t) spread over 8 banks (write conflicts).
// Staging converts NCHW f32 -> bf16 in-kernel with v_cvt_pk (no transpose pass).
#define ROW_BYTES 8320   // 65 pairs * 128
__global__ __launch_bounds__(256) void conv_mfma(const float* __restrict__ x,
                                                 const unsigned short* __restrict__ wb,
                                                 const float* __restrict__ cb,
                                                 unsigned short* __restrict__ h) {
    __shared__ unsigned short w_sm[64 * 296];        // [co][288 + 8 pad]  37,888 B
    __shared__ unsigned char in_sm[4 * ROW_BYTES];   // 33,280 B

    // XCD-chunked swizzle: each XCD gets 8 contiguous y-pairs (16 rows) x all b
    const int id = blockIdx.x;
    const int xcd = id & 7, local = id >> 3;
    const int b = local & 31;
    const int y0 = ((xcd << 3) + (local >> 5)) * 2;

    const int tid = threadIdx.x;
    const int wave = tid >> 6, lane = tid & 63;
    const int lr = lane & 15, kg = lane >> 4;
    const int ro = wave >> 1;            // output row within block (0/1)
    const int px0 = (wave & 1) * 64;     // px half

    f32x4 acc[4][4];
#pragma unroll
    for (int m = 0; m < 4; ++m)
#pragma unroll
        for (int n = 0; n < 4; ++n) acc[m][n] = (f32x4){0.f, 0.f, 0.f, 0.f};

    // A-frag base pointers: 4 m-tiles x 3 dx; (ro+dy)*ROW_BYTES added at use
    const unsigned char* ab[4][3];
#pragma unroll
    for (int m = 0; m < 4; ++m)
#pragma unroll
        for (int dx = 0; dx < 3; ++dx) {
            int xx = px0 + m * 16 + lr + dx;                 // input col, 0..129
            int slot = (((xx & 1) << 2) | kg) ^ ((xx >> 2) & 7);
            ab[m][dx] = in_sm + (xx >> 1) * 128 + slot * 16;
        }
    const unsigned short* bb[4];
#pragma unroll
    for (int n = 0; n < 4; ++n) bb[n] = w_sm + (n * 16 + lr) * 296 + kg * 8;

    for (int cc = 0; cc < 2; ++cc) {
        __syncthreads();
        // ---- stage weights: [co][tap*32 + ci'] (+8 pad), 2304 x 16B ----
        for (int j = tid; j < 2304; j += 256) {
            int q = j & 3, tap = (j >> 2) % 9, co = j / 36;
            uint4 v = *(const uint4*)(wb + (co * 9 + tap) * 64 + cc * 32 + q * 8);
            *(uint4*)(w_sm + co * 296 + tap * 32 + q * 8) = v;
        }
        // ---- stage input: NCHW f32 -> bf16, 4 rows x 128 gx x 32 ci ----
        for (int j = tid; j < 2048; j += 256) {
            int g4 = j & 31, r = (j >> 5) & 3, cp = j >> 7;   // cp 0..15
            int gy = y0 + r - 1;
            int ci = cc * 32 + cp * 2;
            float4 v0 = {0.f, 0.f, 0.f, 0.f}, v1 = v0;
            if (gy >= 0 && gy < 128) {
                const float* base = x + (((size_t)b * 64 + ci) * 128 + gy) * 128 + g4 * 4;
                v0 = *(const float4*)base;
                v1 = *(const float4*)(base + 16384);          // channel ci+1
            }
            float a0[4] = {v0.x, v0.y, v0.z, v0.w};
            float a1[4] = {v1.x, v1.y, v1.z, v1.w};
            const int q = cp >> 2, within = (2 * cp & 7) * 2;
            unsigned char* rowp = in_sm + r * ROW_BYTES;
#pragma unroll
            for (int t = 0; t < 4; ++t) {
                int xx = g4 * 4 + 1 + t;                      // 1..128
                int slot = (((xx & 1) << 2) | q) ^ ((xx >> 2) & 7);
                *(unsigned int*)(rowp + (xx >> 1) * 128 + slot * 16 + within) = pk2bf(a0[t], a1[t]);
            }
        }
        // ---- zero-pad cols xx=0 and xx=129 ----
        for (int j = tid; j < 128; j += 256) {
            int cp = j & 15, r = (j >> 4) & 3, xx = (j >= 64) ? 129 : 0;
            int q = cp >> 2, within = (2 * cp & 7) * 2;
            int slot = (((xx & 1) << 2) | q) ^ ((xx >> 2) & 7);
            *(unsigned int*)(in_sm + r * ROW_BYTES + (xx >> 1) * 128 + slot * 16 + within) = 0u;
        }
        __syncthreads();

        // ---- compute: 9 taps, each one K=32 MFMA step; 4m x 4n per wave ----
#pragma unroll
        for (int t = 0; t < 9; ++t) {
            const int dy = t / 3, dx = t % 3;
            const int aoff = (ro + dy) * ROW_BYTES;
            short8 A0 = *(const short8*)(ab[0][dx] + aoff);
            short8 A1 = *(const short8*)(ab[1][dx] + aoff);
            short8 A2 = *(const short8*)(ab[2][dx] + aoff);
            short8 A3 = *(const short8*)(ab[3][dx] + aoff);
#pragma unroll
            for (int n = 0; n < 4; ++n) {
                short8 B = *(const short8*)(bb[n] + t * 32);
                acc[0][n] = __builtin_amdgcn_mfma_f32_16x16x32_bf16(A0, B, acc[0][n], 0, 0, 0);
                acc[1][n] = __builtin_amdgcn_mfma_f32_16x16x32_bf16(A1, B, acc[1][n], 0, 0, 0);
                acc[2][n] = __builtin_amdgcn_mfma_f32_16x16x32_bf16(A2, B, acc[2][n], 0, 0, 0);
                acc[3][n] = __builtin_amdgcn_mfma_f32_16x16x32_bf16(A3, B, acc[3][n], 0, 0, 0);
            }
        }
    }

    // ---- epilogue: bias + leaky relu, bf16 NHWC store ----
    float bias[4];
#pragma unroll
    for (int n = 0; n < 4; ++n) bias[n] = cb[n * 16 + lr];
    const int y = y0 + ro;
    const size_t hrow = (size_t)(b * 128 + y) * 128;
#pragma unroll
    for (int m = 0; m < 4; ++m)
#pragma unroll
        for (int rr = 0; rr < 4; ++rr) {
            const int p = px0 + m * 16 + kg * 4 + rr;
            unsigned short* hp = h + (hrow + p) * 64 + lr;
#pragma unroll
            for (int n = 0; n < 4; ++n) {
                float v = acc[m][n][rr] + bias[n];
                v = v > 0.0f ? v : NEG_SLOPE * v;
                hp[n * 16] = f2bf(v);
            }
        }
}

// ---------------- gather + (pairs x 768)·(768 x 24) GEMM via MFMA ----------------
__global__ __launch_bounds__(256) void gather_gemm(const unsigned short* __restrict__ h,
                                                   const int* __restrict__ pos,
                                                   const unsigned short* __restrict__ pw,
                                                   const float* __restrict__ pred_b,
                                                   float* __restrict__ out) {
    __shared__ unsigned char pw_lds[32 * 1536];   // 32 rows x 768 bf16, swizzled
    const int tid = threadIdx.x;

    for (int i = tid; i < 3072; i += 256) {       // 3072 chunks of 16B
        int row = i / 96, c = i - row * 96;
        int dst = row * 1536 + ((c * 16) ^ ((row & 7) << 4));
        *(uint4*)(pw_lds + dst) = ((const uint4*)pw)[i];
    }
    __syncthreads();

    const int wave = tid >> 6, lane = tid & 63;
    const int pair_base = blockIdx.x * 64 + wave * 16;
    const int prow = lane & 15;
    const int kgrp = lane >> 4;
    const int pair = pair_base + prow;
    const int b = pair & 31;
    const unsigned short* hb = h + (size_t)b * 16384 * 64;

    const int swz0 = (prow & 7) << 4;
    const unsigned char* bro0 = pw_lds + prow * 1536;
    const unsigned char* bro1 = pw_lds + (prow + 16) * 1536;

    f32x4 acc0 = {0.f, 0.f, 0.f, 0.f};
    f32x4 acc1 = {0.f, 0.f, 0.f, 0.f};

#pragma unroll
    for (int l = 0; l < 12; ++l) {
        int2 pq = ((const int2*)pos)[pair * 12 + l];
        int px = pq.x < 0 ? 0 : (pq.x > 127 ? 127 : pq.x);
        int py = pq.y < 0 ? 0 : (pq.y > 127 ? 127 : pq.y);
        const unsigned short* pix = hb + (((size_t)py << 7) + px) * 64;
#pragma unroll
        for (int half = 0; half < 2; ++half) {
            const int c0 = half * 32 + kgrp * 8;
            short8 a = *(const short8*)(pix + c0);
            const int kb = (l * 64 + half * 32 + kgrp * 8) * 2;
            short8 b0 = *(const short8*)(bro0 + (kb ^ swz0));
            short8 b1 = *(const short8*)(bro1 + (kb ^ swz0));
            acc0 = __builtin_amdgcn_mfma_f32_16x16x32_bf16(a, b0, acc0, 0, 0, 0);
            acc1 = __builtin_amdgcn_mfma_f32_16x16x32_bf16(a, b1, acc1, 0, 0, 0);
        }
    }

    const int o0 = lane & 15;
    const float bias0 = pred_b[o0];
    const float bias1 = (o0 + 16 < 24) ? pred_b[o0 + 16] : 0.0f;
#pragma unroll
    for (int r = 0; r < 4; ++r) {
        const int pout = pair_base + (lane >> 4) * 4 + r;
        out[(size_t)pout * 24 + o0] = acc0[r] + bias0;
        if (o0 + 16 < 24)
            out[(size_t)pout * 24 + o0 + 16] = acc1[r] + bias1;
    }
}

extern "C" void kernel_launch(void* const* d_in, const int* in_sizes, int n_in,
                              void* d_out, int out_size, void* d_ws, size_t ws_size,
                              hipStream_t stream) {
    const float* x      = (const float*)d_in[0];
    const int*   pos    = (const int*)d_in[1];
    const float* conv_w = (const float*)d_in[2];
    const float* conv_b = (const float*)d_in[3];
    const float* pred_w = (const float*)d_in[4];
    const float* pred_b = (const float*)d_in[5];
    float* out = (float*)d_out;

    char* ws = (char*)d_ws;
    unsigned short* h   = (unsigned short*)ws;                        // 67,108,864 B
    unsigned short* wb  = (unsigned short*)(ws + 67108864);           // 73,728 B
    unsigned short* pwb = (unsigned short*)(ws + 67108864 + 73728);   // 49,152 B

    prep_kernel<<<144, 256, 0, stream>>>(conv_w, pred_w, wb, pwb);
    conv_mfma<<<2048, 256, 0, stream>>>(x, wb, conv_b, h);
    gather_gemm<<<500, 256, 0, stream>>>(h, pos, pwb, pred_b, out);
}